// Round 7
// baseline (157.434 us; speedup 1.0000x reference)
//
#include <hip/hip_runtime.h>
#include <hip/hip_bf16.h>

#define IN_FEATS  32
#define OUT_FEATS 64
#define GRIDSZ    8
#define KDIM      512                    // 2 branches * 32 i * 8 k
#define NPB       64                     // nodes per block in kernel A

typedef __attribute__((ext_vector_type(8))) short bf16x8;
typedef __attribute__((ext_vector_type(4))) float f32x4;

static __device__ __forceinline__ unsigned short f2bf(float f) {
    unsigned u = __builtin_bit_cast(unsigned, f);
    return (unsigned short)((u + 0x7fffu + ((u >> 16) & 1u)) >> 16);   // RNE
}
static __device__ __forceinline__ float bf2f(unsigned short h) {
    return __builtin_bit_cast(float, (unsigned)h << 16);
}

// ---------------------------------------------------------------------------
// Kernel A (MFMA): M[n][j] = sum_K Phi[n][K] * W[j][K]
// + fused dst-histogram (grid-stride over edges; atomics overlap MFMA/trig).
// counts[] must be zeroed before this kernel (hipMemsetAsync).
// ---------------------------------------------------------------------------
__global__ __launch_bounds__(256) void fkan_node_msg(
    const float* __restrict__ x,             // [N,32]
    const float* __restrict__ fc,            // [2,64,32,8] fp32
    const int* __restrict__ dst,             // [E]
    unsigned short* __restrict__ M,          // [N,64] bf16 out
    int* __restrict__ counts,                // [N] histogram out
    int n_nodes, int n_edges)
{
    __shared__ __align__(16) short phi[NPB * KDIM];  // 64 KB
    const int tid  = threadIdx.x;
    const int lane = tid & 63;
    const int wid  = tid >> 6;                 // 0..3 -> j-tile
    const int nbase = blockIdx.x * NPB;

    // ---- fused histogram: issued first, hides under compute ----
    for (int e0 = (blockIdx.x * 256 + tid) * 4; e0 < n_edges;
         e0 += gridDim.x * 1024) {
        if (e0 + 3 < n_edges) {
            const int4 d4 = *(const int4*)(dst + e0);
            atomicAdd(&counts[d4.x], 1);
            atomicAdd(&counts[d4.y], 1);
            atomicAdd(&counts[d4.z], 1);
            atomicAdd(&counts[d4.w], 1);
        } else {
            for (int e = e0; e < n_edges; ++e) atomicAdd(&counts[dst[e]], 1);
        }
    }

    // ---- B fragments direct from fc: K = b*256 + i*8 + k ----
    const int j0   = wid * 16;
    const int brow = j0 + (lane & 15);
    const int kofs = 8 * (lane >> 4);
    bf16x8 bfrag[16];
#pragma unroll
    for (int ks = 0; ks < 16; ++ks) {
        const int K  = ks * 32 + kofs;        // 8 consecutive K, same (b,i)
        const int b  = K >> 8;
        const int ik = K & 255;
        const float* p = fc + ((size_t)(b * OUT_FEATS + brow) * 256 + ik);
        const float4 f0 = *(const float4*)p;
        const float4 f1 = *(const float4*)(p + 4);
        bf16x8 t;
        t[0] = (short)f2bf(f0.x); t[1] = (short)f2bf(f0.y);
        t[2] = (short)f2bf(f0.z); t[3] = (short)f2bf(f0.w);
        t[4] = (short)f2bf(f1.x); t[5] = (short)f2bf(f1.y);
        t[6] = (short)f2bf(f1.z); t[7] = (short)f2bf(f1.w);
        bfrag[ks] = t;
    }

    // ---- build Phi (Chebyshev recurrence, XOR-swizzled LDS) ----
    {
        const int node = tid >> 2;
        const int q    = tid & 3;
        const int n    = nbase + node;
        char* rowp = (char*)phi + node * 1024;
        const int sw = (node & 7) << 4;
        float xv[8];
        if (n < n_nodes) {
            const float4 a = *(const float4*)(x + (size_t)n * 32 + q * 8);
            const float4 b = *(const float4*)(x + (size_t)n * 32 + q * 8 + 4);
            xv[0]=a.x; xv[1]=a.y; xv[2]=a.z; xv[3]=a.w;
            xv[4]=b.x; xv[5]=b.y; xv[6]=b.z; xv[7]=b.w;
        } else {
#pragma unroll
            for (int u = 0; u < 8; ++u) xv[u] = 0.f;
        }
#pragma unroll
        for (int u = 0; u < 8; ++u) {
            const int i = q * 8 + u;
            float s1, c1;
            __sincosf(xv[u], &s1, &c1);
            const float twoc = 2.f * c1;
            float cAm = 1.f, sAm = 0.f, cA = c1, sA = s1;
#pragma unroll
            for (int p = 0; p < 4; ++p) {
                const float cB = twoc * cA - cAm;
                const float sB = twoc * sA - sAm;
                const unsigned pc = ((unsigned)f2bf(cB) << 16) | f2bf(cA);
                const unsigned ps = ((unsigned)f2bf(sB) << 16) | f2bf(sA);
                const int Kc = i * 8 + 2 * p;
                *(unsigned*)(rowp + ((Kc * 2) ^ sw))         = pc;
                *(unsigned*)(rowp + (((256 + Kc) * 2) ^ sw)) = ps;
                const float cN = twoc * cB - cA;
                const float sN = twoc * sB - sA;
                cAm = cB; sAm = sB; cA = cN; sA = sN;
            }
        }
    }
    __syncthreads();

    f32x4 acc[4] = {{0.f,0.f,0.f,0.f},{0.f,0.f,0.f,0.f},
                    {0.f,0.f,0.f,0.f},{0.f,0.f,0.f,0.f}};
    const int arow = lane & 15;
    const int sw   = (arow & 7) << 4;
    const int kbyt = 16 * (lane >> 4);
#pragma unroll
    for (int ks = 0; ks < 16; ++ks) {
#pragma unroll
        for (int nt = 0; nt < 4; ++nt) {
            const int row = nt * 16 + arow;
            const bf16x8 afrag = *(const bf16x8*)
                ((const char*)phi + row * 1024 + ((ks * 64 + kbyt) ^ sw));
            acc[nt] = __builtin_amdgcn_mfma_f32_16x16x32_bf16(
                afrag, bfrag[ks], acc[nt], 0, 0, 0);
        }
    }

    const int rem = n_nodes - nbase;
#pragma unroll
    for (int nt = 0; nt < 4; ++nt) {
        const int rbase = nt * 16 + (lane >> 4) * 4;
#pragma unroll
        for (int r = 0; r < 4; ++r) {
            const int node = rbase + r;
            if (node < rem)
                M[(size_t)(nbase + node) * OUT_FEATS + j0 + (lane & 15)] =
                    f2bf(acc[nt][r]);
        }
    }
}

// ---------------------------------------------------------------------------
// Single-kernel exclusive scan: block b sums counts[0..b*256) directly
// (counts is 200 KB, L2-hot) + local 256-wide scan -> offs, cursor.
// ---------------------------------------------------------------------------
__global__ __launch_bounds__(256) void fkan_scan(
    const int* __restrict__ counts, int* __restrict__ offs,
    int* __restrict__ cursor, int n_nodes, int n_edges)
{
    __shared__ int part[256];
    __shared__ int wsum[4];
    const int t = threadIdx.x;
    const int gid = blockIdx.x * 256 + t;

    // sum of all preceding counts
    int pre = 0;
    const int limit = blockIdx.x * 256;
    for (int i = t; i < limit; i += 256) pre += counts[i];
#pragma unroll
    for (int m = 1; m < 64; m <<= 1) pre += __shfl_xor(pre, m);
    if ((t & 63) == 0) wsum[t >> 6] = pre;

    // local scan
    const int c = (gid < n_nodes) ? counts[gid] : 0;
    part[t] = c;
    __syncthreads();
    const int blockbase = wsum[0] + wsum[1] + wsum[2] + wsum[3];
    for (int d = 1; d < 256; d <<= 1) {
        const int v = (t >= d) ? part[t - d] : 0;
        __syncthreads();
        part[t] += v;
        __syncthreads();
    }
    if (gid < n_nodes) {
        const int ex = blockbase + part[t] - c;
        offs[gid] = ex;
        cursor[gid] = ex;
    }
    if (blockIdx.x == 0 && t == 0) offs[n_nodes] = n_edges;
}

// ---------------------------------------------------------------------------
// Bucket fill, XCD-range-filtered, 8 edges/thread, ushort payload.
// ---------------------------------------------------------------------------
__global__ __launch_bounds__(256) void fkan_bucket(
    const int* __restrict__ src, const int* __restrict__ dst,
    int* __restrict__ cursor, unsigned short* __restrict__ ebuf,
    int n_edges, int n8)
{
    const int r    = blockIdx.x & 7;
    const int slab = blockIdx.x >> 3;
    const int base = (slab * 256 + threadIdx.x) * 8;
    if (base >= n_edges) return;
    const int lim = r * n8;
    if (base + 7 < n_edges) {
#pragma unroll
        for (int h = 0; h < 2; ++h) {
            const int4 d4 = *(const int4*)(dst + base + h * 4);
            const int4 s4 = *(const int4*)(src + base + h * 4);
            if ((unsigned)(d4.x - lim) < (unsigned)n8)
                ebuf[atomicAdd(&cursor[d4.x], 1)] = (unsigned short)s4.x;
            if ((unsigned)(d4.y - lim) < (unsigned)n8)
                ebuf[atomicAdd(&cursor[d4.y], 1)] = (unsigned short)s4.y;
            if ((unsigned)(d4.z - lim) < (unsigned)n8)
                ebuf[atomicAdd(&cursor[d4.z], 1)] = (unsigned short)s4.z;
            if ((unsigned)(d4.w - lim) < (unsigned)n8)
                ebuf[atomicAdd(&cursor[d4.w], 1)] = (unsigned short)s4.w;
        }
    } else {
        for (int e = base; e < n_edges; ++e) {
            const int d = dst[e];
            if ((unsigned)(d - lim) < (unsigned)n8)
                ebuf[atomicAdd(&cursor[d], 1)] = (unsigned short)src[e];
        }
    }
}

// ---------------------------------------------------------------------------
// Gather: wave per dst node; 8 edges in flight (8 lanes x 16B per edge row),
// 3-round shfl-xor reduce, float4 stores.
// ---------------------------------------------------------------------------
__global__ __launch_bounds__(256) void fkan_gather(
    const int* __restrict__ offs, const unsigned short* __restrict__ ebuf,
    const unsigned short* __restrict__ M, const float* __restrict__ bias,
    float* __restrict__ out, int n_nodes)
{
    const int lane = threadIdx.x & 63;
    const int node = blockIdx.x * 4 + (threadIdx.x >> 6);
    if (node >= n_nodes) return;
    const int beg = offs[node], end = offs[node + 1];
    const int sub  = lane >> 3;        // 0..7 edge slot
    const int colb = (lane & 7) * 8;   // 8-col group
    float a0=0.f,a1=0.f,a2=0.f,a3=0.f,a4=0.f,a5=0.f,a6=0.f,a7=0.f;
    for (int e = beg; e < end; e += 8) {
        const int ee = e + sub;
        if (ee < end) {
            const int s = ebuf[ee];
            const bf16x8 v = *(const bf16x8*)(M + (size_t)s * OUT_FEATS + colb);
            a0 += bf2f((unsigned short)v[0]); a1 += bf2f((unsigned short)v[1]);
            a2 += bf2f((unsigned short)v[2]); a3 += bf2f((unsigned short)v[3]);
            a4 += bf2f((unsigned short)v[4]); a5 += bf2f((unsigned short)v[5]);
            a6 += bf2f((unsigned short)v[6]); a7 += bf2f((unsigned short)v[7]);
        }
    }
#pragma unroll
    for (int m = 8; m <= 32; m <<= 1) {
        a0 += __shfl_xor(a0, m); a1 += __shfl_xor(a1, m);
        a2 += __shfl_xor(a2, m); a3 += __shfl_xor(a3, m);
        a4 += __shfl_xor(a4, m); a5 += __shfl_xor(a5, m);
        a6 += __shfl_xor(a6, m); a7 += __shfl_xor(a7, m);
    }
    if (sub == 0) {
        const float4 b0 = *(const float4*)(bias + colb);
        const float4 b1 = *(const float4*)(bias + colb + 4);
        float4 o0; o0.x = a0 + b0.x; o0.y = a1 + b0.y; o0.z = a2 + b0.z; o0.w = a3 + b0.w;
        float4 o1; o1.x = a4 + b1.x; o1.y = a5 + b1.y; o1.z = a6 + b1.z; o1.w = a7 + b1.w;
        *(float4*)(out + (size_t)node * OUT_FEATS + colb)     = o0;
        *(float4*)(out + (size_t)node * OUT_FEATS + colb + 4) = o1;
    }
}

// ---------------------------------------------------------------------------
extern "C" void kernel_launch(void* const* d_in, const int* in_sizes, int n_in,
                              void* d_out, int out_size, void* d_ws, size_t ws_size,
                              hipStream_t stream)
{
    const float* x    = (const float*)d_in[0];   // [N,32]
    const int*   src  = (const int*)d_in[1];     // [E]
    const int*   dst  = (const int*)d_in[2];     // [E]
    const float* fc   = (const float*)d_in[3];   // [2,64,32,8]
    const float* bias = (const float*)d_in[4];   // [64]
    float* out = (float*)d_out;                  // [N,64]

    const int n_nodes = in_sizes[0] / IN_FEATS;
    const int n_edges = in_sizes[1];
    const int nblk    = (n_nodes + 255) / 256;
    const int n8      = (n_nodes + 7) / 8;       // nodes per XCD range

    // workspace layout
    char* ws = (char*)d_ws;
    unsigned short* M = (unsigned short*)ws;                        // N*64*2 B
    int* offs   = (int*)(ws + (size_t)n_nodes * OUT_FEATS * 2);
    int* cursor = offs + (n_nodes + 1);
    int* counts = cursor + n_nodes;
    unsigned short* ebuf = (unsigned short*)(counts + n_nodes);     // E ushort

    // zero the histogram (graph-capture-safe async memset)
    hipMemsetAsync(counts, 0, (size_t)n_nodes * sizeof(int), stream);

    // A: per-node messages via MFMA + fused dst-histogram
    fkan_node_msg<<<(n_nodes + NPB - 1) / NPB, 256, 0, stream>>>(
        x, fc, dst, M, counts, n_nodes, n_edges);

    // exclusive scan -> offs, cursor
    fkan_scan<<<nblk, 256, 0, stream>>>(counts, offs, cursor, n_nodes, n_edges);

    // bucket fill (XCD-filtered)
    fkan_bucket<<<8 * ((n_edges + 2047) / 2048), 256, 0, stream>>>(
        src, dst, cursor, ebuf, n_edges, n8);

    // gather + bias
    fkan_gather<<<(n_nodes + 3) / 4, 256, 0, stream>>>(offs, ebuf, M, bias, out, n_nodes);
}